// Round 3
// baseline (90.314 us; speedup 1.0000x reference)
//
#include <hip/hip_runtime.h>

// Problem geometry (fixed by reference):
//   x: (32, 3, 224, 224) f32, target: (32,) i32, W: (60,3,1,1) f32, b: (60,) f32
//   out: (32, 3, 224, 224) f32
#define HW    50176   // 224*224
#define HW4   12544   // HW/4 (float4 granules per channel)
#define NB    32      // batch
#define BPN   49      // blocks per sample: 12544 / 256
#define NTHR  256
#define FINF  __int_as_float(0x7f800000)

// ws layout:
//   [0, 128)                : unsigned cnt[NB]   (per-sample arrival counter)
//   [128, 128 + 1568*6*4)   : float partials[1568][6]  {min0,min1,min2,max0,max1,max2}
// cnt is zeroed by init_kernel every call; partials are unconditionally
// rewritten every call -> deterministic across graph replays.

__global__ void init_kernel(unsigned* __restrict__ cnt) {
    if (threadIdx.x < NB) cnt[threadIdx.x] = 0u;
}

__global__ __launch_bounds__(NTHR, 8) void fused_kernel(
    const float* __restrict__ x, const int* __restrict__ target,
    const float* __restrict__ W, const float* __restrict__ b,
    unsigned* __restrict__ cnt, float* __restrict__ partials,
    float* __restrict__ out)
{
    const int blk   = blockIdx.x;
    const int n     = blk / BPN;
    const int chunk = blk % BPN;
    const int idx4  = chunk * NTHR + threadIdx.x;   // [0, HW4)

    const float4* xb = (const float4*)(x + (size_t)n * 3 * HW);
    float4 x0 = xb[idx4];
    float4 x1 = xb[idx4 + HW4];
    float4 x2 = xb[idx4 + 2 * HW4];

    const int t = target[n];

    // ---- phase 1: per-thread conv + min/max, block reduce ----
    float w0[3], w1[3], w2[3], bk[3];
#pragma unroll
    for (int k = 0; k < 3; ++k) {
        const int oc = t * 3 + k;
        w0[k] = W[oc * 3 + 0];
        w1[k] = W[oc * 3 + 1];
        w2[k] = W[oc * 3 + 2];
        bk[k] = b[oc];
    }

    float mn[3], mx[3];
#pragma unroll
    for (int k = 0; k < 3; ++k) {
        float p0 = fmaf(w0[k], x0.x, fmaf(w1[k], x1.x, fmaf(w2[k], x2.x, bk[k])));
        float p1 = fmaf(w0[k], x0.y, fmaf(w1[k], x1.y, fmaf(w2[k], x2.y, bk[k])));
        float p2 = fmaf(w0[k], x0.z, fmaf(w1[k], x1.z, fmaf(w2[k], x2.z, bk[k])));
        float p3 = fmaf(w0[k], x0.w, fmaf(w1[k], x1.w, fmaf(w2[k], x2.w, bk[k])));
        mn[k] = fminf(fminf(p0, p1), fminf(p2, p3));
        mx[k] = fmaxf(fmaxf(p0, p1), fmaxf(p2, p3));
    }

#pragma unroll
    for (int off = 32; off >= 1; off >>= 1) {
#pragma unroll
        for (int k = 0; k < 3; ++k) {
            mn[k] = fminf(mn[k], __shfl_xor(mn[k], off, 64));
            mx[k] = fmaxf(mx[k], __shfl_xor(mx[k], off, 64));
        }
    }

    __shared__ float smn[4][3], smx[4][3];
    const int lane = threadIdx.x & 63;
    const int wave = threadIdx.x >> 6;
    if (lane == 0) {
#pragma unroll
        for (int k = 0; k < 3; ++k) { smn[wave][k] = mn[k]; smx[wave][k] = mx[k]; }
    }
    __syncthreads();

    // ---- phase 2: publish block partial, per-sample device barrier ----
    if (threadIdx.x == 0) {
        float* dst = partials + (size_t)blk * 6;
#pragma unroll
        for (int k = 0; k < 3; ++k) {
            dst[k]     = fminf(fminf(smn[0][k], smn[1][k]), fminf(smn[2][k], smn[3][k]));
            dst[k + 3] = fmaxf(fmaxf(smx[0][k], smx[1][k]), fmaxf(smx[2][k], smx[3][k]));
        }
        __threadfence();  // make partials visible device-wide before signaling
        __hip_atomic_fetch_add(&cnt[n], 1u, __ATOMIC_ACQ_REL, __HIP_MEMORY_SCOPE_AGENT);
        // All 49 blocks of sample n are co-resident (2048 block slots >= 1568
        // total blocks at launch_bounds(256,8)) -> spin cannot deadlock.
        while (__hip_atomic_load(&cnt[n], __ATOMIC_ACQUIRE, __HIP_MEMORY_SCOPE_AGENT) < BPN) { }
    }
    __syncthreads();

    // ---- phase 3: reduce this sample's 49 partials (L2/L3-hot) ----
    __shared__ float s_min[3], s_max[3];
    if (threadIdx.x < 64) {
        float rmn[3] = { FINF,  FINF,  FINF};
        float rmx[3] = {-FINF, -FINF, -FINF};
        if (threadIdx.x < BPN) {
            const float* p = partials + (size_t)(n * BPN + threadIdx.x) * 6;
#pragma unroll
            for (int k = 0; k < 3; ++k) { rmn[k] = p[k]; rmx[k] = p[k + 3]; }
        }
#pragma unroll
        for (int off = 32; off >= 1; off >>= 1) {
#pragma unroll
            for (int k = 0; k < 3; ++k) {
                rmn[k] = fminf(rmn[k], __shfl_xor(rmn[k], off, 64));
                rmx[k] = fmaxf(rmx[k], __shfl_xor(rmx[k], off, 64));
            }
        }
        if (threadIdx.x == 0) {
#pragma unroll
            for (int k = 0; k < 3; ++k) { s_min[k] = rmn[k]; s_max[k] = rmx[k]; }
        }
    }
    __syncthreads();

    // ---- phase 4: normalize from registers, store ----
#pragma unroll
    for (int k = 0; k < 3; ++k) {
        const float pmin = s_min[k];
        const float inv  = 1.0f / (s_max[k] - pmin);

        float p0 = fmaf(w0[k], x0.x, fmaf(w1[k], x1.x, fmaf(w2[k], x2.x, bk[k])));
        float p1 = fmaf(w0[k], x0.y, fmaf(w1[k], x1.y, fmaf(w2[k], x2.y, bk[k])));
        float p2 = fmaf(w0[k], x0.z, fmaf(w1[k], x1.z, fmaf(w2[k], x2.z, bk[k])));
        float p3 = fmaf(w0[k], x0.w, fmaf(w1[k], x1.w, fmaf(w2[k], x2.w, bk[k])));

        float4 o;
        o.x = ((p0 - pmin) * inv - 0.5f) * 2.0f;
        o.y = ((p1 - pmin) * inv - 0.5f) * 2.0f;
        o.z = ((p2 - pmin) * inv - 0.5f) * 2.0f;
        o.w = ((p3 - pmin) * inv - 0.5f) * 2.0f;
        // MAX_PERTURBATION / 128.0 == 1.0 — no extra scale needed.

        float4* ob = (float4*)(out + (size_t)n * 3 * HW + (size_t)k * HW);
        ob[idx4] = o;
    }
}

extern "C" void kernel_launch(void* const* d_in, const int* in_sizes, int n_in,
                              void* d_out, int out_size, void* d_ws, size_t ws_size,
                              hipStream_t stream) {
    const float* x      = (const float*)d_in[0];
    const int*   target = (const int*)d_in[1];
    const float* W      = (const float*)d_in[2];
    const float* b      = (const float*)d_in[3];
    float*       out    = (float*)d_out;

    unsigned* cnt      = (unsigned*)d_ws;
    float*    partials = (float*)((char*)d_ws + 128);

    init_kernel<<<1, 64, 0, stream>>>(cnt);
    fused_kernel<<<NB * BPN, NTHR, 0, stream>>>(x, target, W, b, cnt, partials, out);
}

// Round 4
// 40.315 us; speedup vs baseline: 2.2402x; 2.2402x over previous
//
#include <hip/hip_runtime.h>

// Problem geometry (fixed by reference):
//   x: (32, 3, 224, 224) f32, target: (32,) i32, W: (60,3,1,1) f32, b: (60,) f32
//   out: (32, 3, 224, 224) f32
#define HW    50176   // 224*224
#define HW4   12544   // HW/4 (float4 granules per channel)
#define NB    32      // batch
#define BPS   7       // blocks per sample
#define NBLK  (NB * BPS)          // 224 blocks <= 256 CUs -> all co-resident at ANY vgpr count
#define JPT   7       // float4 granules per thread per channel: 12544 / (7*256)
#define NTHR  256
#define FINF  __int_as_float(0x7f800000)

// ws layout:
//   [0, 2048)      : unsigned cnt[32][16]  (per-sample arrival counter, 64B padded)
//   [2048, ...)    : float partials[224][6] {min0,min1,min2,max0,max1,max2}
// cnt zeroed by init_kernel every call; partials unconditionally rewritten
// every call -> deterministic across graph replays.

__global__ void init_kernel(unsigned* __restrict__ cnt) {
    cnt[threadIdx.x] = 0u;   // 512 threads zero 2KB
}

__global__ __launch_bounds__(NTHR, 1) void fused_kernel(
    const float* __restrict__ x, const int* __restrict__ target,
    const float* __restrict__ W, const float* __restrict__ b,
    unsigned* __restrict__ cnt, float* __restrict__ partials,
    float* __restrict__ out)
{
    const int blk = blockIdx.x;
    const int n   = blk / BPS;
    const int sub = blk % BPS;
    const int tid = threadIdx.x;

    const int t = target[n];
    float w0[3], w1[3], w2[3], bk[3];
#pragma unroll
    for (int k = 0; k < 3; ++k) {
        const int oc = t * 3 + k;
        w0[k] = W[oc * 3 + 0];
        w1[k] = W[oc * 3 + 1];
        w2[k] = W[oc * 3 + 2];
        bk[k] = b[oc];
    }

    // ---- phase 1: load this block's 7x256 float4 per channel, conv to regs ----
    const float4* xb = (const float4*)(x + (size_t)n * 3 * HW);
    float4 p[3][JPT];   // conv results, held in VGPRs until phase 4
    float mn[3] = { FINF,  FINF,  FINF};
    float mx[3] = {-FINF, -FINF, -FINF};

#pragma unroll
    for (int j = 0; j < JPT; ++j) {
        const int i4 = sub * (JPT * NTHR) + j * NTHR + tid;
        float4 x0 = xb[i4];
        float4 x1 = xb[i4 + HW4];
        float4 x2 = xb[i4 + 2 * HW4];
#pragma unroll
        for (int k = 0; k < 3; ++k) {
            float4 pv;
            pv.x = fmaf(w0[k], x0.x, fmaf(w1[k], x1.x, fmaf(w2[k], x2.x, bk[k])));
            pv.y = fmaf(w0[k], x0.y, fmaf(w1[k], x1.y, fmaf(w2[k], x2.y, bk[k])));
            pv.z = fmaf(w0[k], x0.z, fmaf(w1[k], x1.z, fmaf(w2[k], x2.z, bk[k])));
            pv.w = fmaf(w0[k], x0.w, fmaf(w1[k], x1.w, fmaf(w2[k], x2.w, bk[k])));
            p[k][j] = pv;
            mn[k] = fminf(mn[k], fminf(fminf(pv.x, pv.y), fminf(pv.z, pv.w)));
            mx[k] = fmaxf(mx[k], fmaxf(fmaxf(pv.x, pv.y), fmaxf(pv.z, pv.w)));
        }
    }

    // ---- block reduce: wave butterfly + LDS across 4 waves ----
#pragma unroll
    for (int off = 32; off >= 1; off >>= 1) {
#pragma unroll
        for (int k = 0; k < 3; ++k) {
            mn[k] = fminf(mn[k], __shfl_xor(mn[k], off, 64));
            mx[k] = fmaxf(mx[k], __shfl_xor(mx[k], off, 64));
        }
    }
    __shared__ float smn[4][3], smx[4][3];
    const int lane = tid & 63;
    const int wave = tid >> 6;
    if (lane == 0) {
#pragma unroll
        for (int k = 0; k < 3; ++k) { smn[wave][k] = mn[k]; smx[wave][k] = mx[k]; }
    }
    __syncthreads();

    // ---- phase 2: publish partial; per-sample barrier over 7 co-resident blocks ----
    unsigned* my_cnt = &cnt[n * 16];
    if (tid == 0) {
        float* dst = partials + (size_t)blk * 6;
#pragma unroll
        for (int k = 0; k < 3; ++k) {
            dst[k]     = fminf(fminf(smn[0][k], smn[1][k]), fminf(smn[2][k], smn[3][k]));
            dst[k + 3] = fmaxf(fmaxf(smx[0][k], smx[1][k]), fmaxf(smx[2][k], smx[3][k]));
        }
        __threadfence();
        __hip_atomic_fetch_add(my_cnt, 1u, __ATOMIC_ACQ_REL, __HIP_MEMORY_SCOPE_AGENT);
    }
    // All threads spin. cnt==7 implies all 7 blocks (incl. ours) published.
    // 224 blocks <= 256 CUs -> all blocks resident -> no deadlock.
    while (__hip_atomic_load(my_cnt, __ATOMIC_ACQUIRE, __HIP_MEMORY_SCOPE_AGENT) < BPS) {
        __builtin_amdgcn_s_sleep(1);
    }

    // ---- phase 3: every thread reduces the sample's 7 partials (L2-hot broadcast) ----
    float fmn[3] = { FINF,  FINF,  FINF};
    float fmx[3] = {-FINF, -FINF, -FINF};
    const float* pp = partials + (size_t)n * BPS * 6;
#pragma unroll
    for (int s = 0; s < BPS; ++s) {
#pragma unroll
        for (int k = 0; k < 3; ++k) {
            fmn[k] = fminf(fmn[k], pp[s * 6 + k]);
            fmx[k] = fmaxf(fmx[k], pp[s * 6 + k + 3]);
        }
    }

    // ---- phase 4: normalize from registers, store ----
#pragma unroll
    for (int k = 0; k < 3; ++k) {
        const float pmin = fmn[k];
        const float inv  = 1.0f / (fmx[k] - pmin);
        float4* ob = (float4*)(out + (size_t)n * 3 * HW + (size_t)k * HW);
#pragma unroll
        for (int j = 0; j < JPT; ++j) {
            const int i4 = sub * (JPT * NTHR) + j * NTHR + tid;
            float4 pv = p[k][j];
            float4 o;
            o.x = ((pv.x - pmin) * inv - 0.5f) * 2.0f;
            o.y = ((pv.y - pmin) * inv - 0.5f) * 2.0f;
            o.z = ((pv.z - pmin) * inv - 0.5f) * 2.0f;
            o.w = ((pv.w - pmin) * inv - 0.5f) * 2.0f;
            // MAX_PERTURBATION / 128.0 == 1.0 — no extra scale needed.
            ob[i4] = o;
        }
    }
}

extern "C" void kernel_launch(void* const* d_in, const int* in_sizes, int n_in,
                              void* d_out, int out_size, void* d_ws, size_t ws_size,
                              hipStream_t stream) {
    const float* x      = (const float*)d_in[0];
    const int*   target = (const int*)d_in[1];
    const float* W      = (const float*)d_in[2];
    const float* b      = (const float*)d_in[3];
    float*       out    = (float*)d_out;

    unsigned* cnt      = (unsigned*)d_ws;
    float*    partials = (float*)((char*)d_ws + 2048);

    init_kernel<<<1, 512, 0, stream>>>(cnt);
    fused_kernel<<<NBLK, NTHR, 0, stream>>>(x, target, W, b, cnt, partials, out);
}

// Round 5
// 29.924 us; speedup vs baseline: 3.0181x; 1.3473x over previous
//
#include <hip/hip_runtime.h>

// Problem geometry (fixed by reference):
//   x: (32, 3, 224, 224) f32, target: (32,) i32, W: (60,3,1,1) f32, b: (60,) f32
//   out: (32, 3, 224, 224) f32
#define HW    50176   // 224*224
#define HW4   12544   // HW/4 (float4 granules per channel)
#define NB    32      // batch
#define BPN   49      // blocks per sample
#define NTHR  256
#define FINF  __int_as_float(0x7f800000)

// ws layout (all uints):
//   cnt[32][16]  : per-sample arrival counters, 64B padded        (2 KB)
//   gmm[32][16]  : per-sample [0..2]=enc(min_k), [3..5]=enc(max_k) (2 KB)
// Both fully re-initialized by init_kernel every call -> deterministic
// across graph replays and independent of d_ws poison state.

// Monotone order-preserving encoding of float into uint so atomic umin/umax work.
__device__ __forceinline__ unsigned encf(float f) {
    unsigned u = __float_as_uint(f);
    return (u & 0x80000000u) ? ~u : (u | 0x80000000u);
}
__device__ __forceinline__ float decf(unsigned k) {
    unsigned u = (k & 0x80000000u) ? (k & 0x7FFFFFFFu) : ~k;
    return __uint_as_float(u);
}

__global__ void init_kernel(unsigned* __restrict__ ws) {
    const int j = threadIdx.x;           // 0..511
    ws[j] = 0u;                          // cnt[32][16] = 0
    const int f = j & 15;
    ws[512 + j] = (f < 3) ? 0xFFFFFFFFu : 0u;  // gmm: min-identity / max-identity
}

__global__ __launch_bounds__(NTHR, 8) void fused_kernel(
    const float* __restrict__ x, const int* __restrict__ target,
    const float* __restrict__ W, const float* __restrict__ b,
    unsigned* __restrict__ ws, float* __restrict__ out)
{
    const int blk   = blockIdx.x;
    const int n     = blk / BPN;
    const int chunk = blk % BPN;
    const int idx4  = chunk * NTHR + threadIdx.x;   // [0, HW4)
    const int tid   = threadIdx.x;

    unsigned* cnt = ws + n * 16;
    unsigned* gmm = ws + 512 + n * 16;

    const int t = target[n];
    float w0[3], w1[3], w2[3], bk[3];
#pragma unroll
    for (int k = 0; k < 3; ++k) {
        const int oc = t * 3 + k;
        w0[k] = W[oc * 3 + 0];
        w1[k] = W[oc * 3 + 1];
        w2[k] = W[oc * 3 + 2];
        bk[k] = b[oc];
    }

    // ---- phase 1: read x, conv, block-reduce min/max ----
    const float4* xb = (const float4*)(x + (size_t)n * 3 * HW);
    float4 x0 = xb[idx4];
    float4 x1 = xb[idx4 + HW4];
    float4 x2 = xb[idx4 + 2 * HW4];

    float mn[3], mx[3];
#pragma unroll
    for (int k = 0; k < 3; ++k) {
        float p0 = fmaf(w0[k], x0.x, fmaf(w1[k], x1.x, fmaf(w2[k], x2.x, bk[k])));
        float p1 = fmaf(w0[k], x0.y, fmaf(w1[k], x1.y, fmaf(w2[k], x2.y, bk[k])));
        float p2 = fmaf(w0[k], x0.z, fmaf(w1[k], x1.z, fmaf(w2[k], x2.z, bk[k])));
        float p3 = fmaf(w0[k], x0.w, fmaf(w1[k], x1.w, fmaf(w2[k], x2.w, bk[k])));
        mn[k] = fminf(fminf(p0, p1), fminf(p2, p3));
        mx[k] = fmaxf(fmaxf(p0, p1), fmaxf(p2, p3));
    }
#pragma unroll
    for (int off = 32; off >= 1; off >>= 1) {
#pragma unroll
        for (int k = 0; k < 3; ++k) {
            mn[k] = fminf(mn[k], __shfl_xor(mn[k], off, 64));
            mx[k] = fmaxf(mx[k], __shfl_xor(mx[k], off, 64));
        }
    }
    __shared__ float smn[4][3], smx[4][3];
    const int lane = tid & 63;
    const int wave = tid >> 6;
    if (lane == 0) {
#pragma unroll
        for (int k = 0; k < 3; ++k) { smn[wave][k] = mn[k]; smx[wave][k] = mx[k]; }
    }
    __syncthreads();

    // ---- phase 2: publish via relaxed agent atomics (no fences, no L2 inv),
    //      then bump counter; thread0 spins with relaxed loads ----
    __shared__ float s_min[3], s_max[3];
    if (tid == 0) {
#pragma unroll
        for (int k = 0; k < 3; ++k) {
            float m = fminf(fminf(smn[0][k], smn[1][k]), fminf(smn[2][k], smn[3][k]));
            float M = fmaxf(fmaxf(smx[0][k], smx[1][k]), fmaxf(smx[2][k], smx[3][k]));
            __hip_atomic_fetch_min(&gmm[k],     encf(m), __ATOMIC_RELAXED, __HIP_MEMORY_SCOPE_AGENT);
            __hip_atomic_fetch_max(&gmm[k + 3], encf(M), __ATOMIC_RELAXED, __HIP_MEMORY_SCOPE_AGENT);
        }
        // Ensure the min/max atomics are complete at the coherence point
        // before the arrival increment can be observed.
        asm volatile("s_waitcnt vmcnt(0)" ::: "memory");
        __hip_atomic_fetch_add(cnt, 1u, __ATOMIC_RELAXED, __HIP_MEMORY_SCOPE_AGENT);

        // All 1568 blocks co-resident (8 blocks/CU @ <=64 VGPR, 512B LDS) -> safe.
        while (__hip_atomic_load(cnt, __ATOMIC_RELAXED, __HIP_MEMORY_SCOPE_AGENT) < BPN) {
            __builtin_amdgcn_s_sleep(2);
        }
#pragma unroll
        for (int k = 0; k < 3; ++k) {
            s_min[k] = decf(__hip_atomic_load(&gmm[k],     __ATOMIC_RELAXED, __HIP_MEMORY_SCOPE_AGENT));
            s_max[k] = decf(__hip_atomic_load(&gmm[k + 3], __ATOMIC_RELAXED, __HIP_MEMORY_SCOPE_AGENT));
        }
    }
    __syncthreads();

    // ---- phase 3: re-read own chunk (XCD-L2 hot, never invalidated),
    //      recompute conv, normalize, store ----
#pragma unroll
    for (int k = 0; k < 3; ++k) {
        const float pmin = s_min[k];
        const float inv  = 1.0f / (s_max[k] - pmin);

        float p0 = fmaf(w0[k], x0.x, fmaf(w1[k], x1.x, fmaf(w2[k], x2.x, bk[k])));
        float p1 = fmaf(w0[k], x0.y, fmaf(w1[k], x1.y, fmaf(w2[k], x2.y, bk[k])));
        float p2 = fmaf(w0[k], x0.z, fmaf(w1[k], x1.z, fmaf(w2[k], x2.z, bk[k])));
        float p3 = fmaf(w0[k], x0.w, fmaf(w1[k], x1.w, fmaf(w2[k], x2.w, bk[k])));

        float4 o;
        o.x = ((p0 - pmin) * inv - 0.5f) * 2.0f;
        o.y = ((p1 - pmin) * inv - 0.5f) * 2.0f;
        o.z = ((p2 - pmin) * inv - 0.5f) * 2.0f;
        o.w = ((p3 - pmin) * inv - 0.5f) * 2.0f;
        // MAX_PERTURBATION / 128.0 == 1.0 — no extra scale needed.

        float4* ob = (float4*)(out + (size_t)n * 3 * HW + (size_t)k * HW);
        ob[idx4] = o;
    }
}

extern "C" void kernel_launch(void* const* d_in, const int* in_sizes, int n_in,
                              void* d_out, int out_size, void* d_ws, size_t ws_size,
                              hipStream_t stream) {
    const float* x      = (const float*)d_in[0];
    const int*   target = (const int*)d_in[1];
    const float* W      = (const float*)d_in[2];
    const float* b      = (const float*)d_in[3];
    float*       out    = (float*)d_out;
    unsigned*    ws     = (unsigned*)d_ws;

    init_kernel<<<1, 512, 0, stream>>>(ws);
    fused_kernel<<<NB * BPN, NTHR, 0, stream>>>(x, target, W, b, ws, out);
}

// Round 6
// 21.782 us; speedup vs baseline: 4.1463x; 1.3738x over previous
//
#include <hip/hip_runtime.h>

// Problem geometry (fixed by reference):
//   x: (32, 3, 224, 224) f32, target: (32,) i32, W: (60,3,1,1) f32, b: (60,) f32
//   out: (32, 3, 224, 224) f32
#define HW    50176   // 224*224
#define HW4   12544   // float4 granules per channel
#define NB    32      // batch
#define BPS   8       // blocks per sample
#define NBLK  (NB * BPS)      // 256 blocks -> provably all co-resident (<=1 per CU needed)
#define NTHR  1024
#define TPS   (BPS * NTHR)    // 8192 threads per sample
#define REM   (HW4 - TPS)     // 4352: threads with sid < REM carry a 2nd granule (wave-uniform: 4352%64==0)
#define FINF  __int_as_float(0x7f800000)

// ws layout:
//   u64 partials[256][8]  : per-block slot, 3 u64 used (packed {max_enc,min_enc} per channel),
//                           64B stride to avoid false sharing            (16 KB)
//   u32 cnt[32][16]       : per-sample arrival counters, 64B padded, at +16384 (2 KB)
// cnt zeroed by init_kernel every call; partials fully rewritten before being
// read each call (counter protocol) -> deterministic across graph replays.

__device__ __forceinline__ unsigned encf(float f) {
    unsigned u = __float_as_uint(f);
    return (u & 0x80000000u) ? ~u : (u | 0x80000000u);
}
__device__ __forceinline__ float decf(unsigned k) {
    unsigned u = (k & 0x80000000u) ? (k & 0x7FFFFFFFu) : ~k;
    return __uint_as_float(u);
}

__global__ void init_kernel(unsigned* __restrict__ cnt) {
    cnt[threadIdx.x] = 0u;   // 512 threads zero cnt[32][16]
}

__global__ __launch_bounds__(NTHR, 4) void fused_kernel(
    const float* __restrict__ x, const int* __restrict__ target,
    const float* __restrict__ W, const float* __restrict__ b,
    unsigned long long* __restrict__ partials, unsigned* __restrict__ cnt,
    float* __restrict__ out)
{
    const int blk  = blockIdx.x;
    const int n    = blk >> 3;
    const int sub  = blk & 7;
    const int tid  = threadIdx.x;
    const int sid  = sub * NTHR + tid;      // [0, 8192) within sample
    const bool has2 = (sid < REM);          // wave-uniform predicate

    const int t = target[n];
    float w0[3], w1[3], w2[3], bk[3];
#pragma unroll
    for (int k = 0; k < 3; ++k) {
        const int oc = t * 3 + k;
        w0[k] = W[oc * 3 + 0];
        w1[k] = W[oc * 3 + 1];
        w2[k] = W[oc * 3 + 2];
        bk[k] = b[oc];
    }

    // ---- phase 1: load 1-2 granules x 3 channels into registers ----
    const float4* xp = (const float4*)(x + (size_t)n * 3 * HW);
    float4 xA[3], xB[3];
    xA[0] = xp[sid];
    xA[1] = xp[sid + HW4];
    xA[2] = xp[sid + 2 * HW4];
    if (has2) {
        xB[0] = xp[sid + TPS];
        xB[1] = xp[sid + TPS + HW4];
        xB[2] = xp[sid + TPS + 2 * HW4];
    }

    float mn[3], mx[3];
#pragma unroll
    for (int k = 0; k < 3; ++k) {
        float p0 = fmaf(w0[k], xA[0].x, fmaf(w1[k], xA[1].x, fmaf(w2[k], xA[2].x, bk[k])));
        float p1 = fmaf(w0[k], xA[0].y, fmaf(w1[k], xA[1].y, fmaf(w2[k], xA[2].y, bk[k])));
        float p2 = fmaf(w0[k], xA[0].z, fmaf(w1[k], xA[1].z, fmaf(w2[k], xA[2].z, bk[k])));
        float p3 = fmaf(w0[k], xA[0].w, fmaf(w1[k], xA[1].w, fmaf(w2[k], xA[2].w, bk[k])));
        mn[k] = fminf(fminf(p0, p1), fminf(p2, p3));
        mx[k] = fmaxf(fmaxf(p0, p1), fmaxf(p2, p3));
        if (has2) {
            float q0 = fmaf(w0[k], xB[0].x, fmaf(w1[k], xB[1].x, fmaf(w2[k], xB[2].x, bk[k])));
            float q1 = fmaf(w0[k], xB[0].y, fmaf(w1[k], xB[1].y, fmaf(w2[k], xB[2].y, bk[k])));
            float q2 = fmaf(w0[k], xB[0].z, fmaf(w1[k], xB[1].z, fmaf(w2[k], xB[2].z, bk[k])));
            float q3 = fmaf(w0[k], xB[0].w, fmaf(w1[k], xB[1].w, fmaf(w2[k], xB[2].w, bk[k])));
            mn[k] = fminf(mn[k], fminf(fminf(q0, q1), fminf(q2, q3)));
            mx[k] = fmaxf(mx[k], fmaxf(fmaxf(q0, q1), fmaxf(q2, q3)));
        }
    }

    // ---- block reduce: wave butterfly, then 16 wave-leaders via LDS ----
#pragma unroll
    for (int off = 32; off >= 1; off >>= 1) {
#pragma unroll
        for (int k = 0; k < 3; ++k) {
            mn[k] = fminf(mn[k], __shfl_xor(mn[k], off, 64));
            mx[k] = fmaxf(mx[k], __shfl_xor(mx[k], off, 64));
        }
    }
    __shared__ float smn[16][3], smx[16][3];
    const int lane = tid & 63;
    const int wv   = tid >> 6;
    if (lane == 0) {
#pragma unroll
        for (int k = 0; k < 3; ++k) { smn[wv][k] = mn[k]; smx[wv][k] = mx[k]; }
    }
    __syncthreads();

    // ---- phase 2: wave 0 reduces 16 partials; thread 0 runs the 8-block barrier ----
    __shared__ float s_min[3], s_max[3];
    if (tid < 64) {
        float rmn[3] = { FINF,  FINF,  FINF};
        float rmx[3] = {-FINF, -FINF, -FINF};
        if (tid < 16) {
#pragma unroll
            for (int k = 0; k < 3; ++k) { rmn[k] = smn[tid][k]; rmx[k] = smx[tid][k]; }
        }
#pragma unroll
        for (int off = 8; off >= 1; off >>= 1) {
#pragma unroll
            for (int k = 0; k < 3; ++k) {
                rmn[k] = fminf(rmn[k], __shfl_xor(rmn[k], off, 64));
                rmx[k] = fmaxf(rmx[k], __shfl_xor(rmx[k], off, 64));
            }
        }
        if (tid == 0) {
            // publish own slot: 3 packed u64 atomic stores (write-through, no RMW)
            unsigned long long* slot = partials + (size_t)blk * 8;
#pragma unroll
            for (int k = 0; k < 3; ++k) {
                unsigned long long v =
                    ((unsigned long long)encf(rmx[k]) << 32) | (unsigned long long)encf(rmn[k]);
                __hip_atomic_store(&slot[k], v, __ATOMIC_RELAXED, __HIP_MEMORY_SCOPE_AGENT);
            }
            asm volatile("s_waitcnt vmcnt(0)" ::: "memory");  // stores at coherence point first
            unsigned* c = cnt + n * 16;
            __hip_atomic_fetch_add(c, 1u, __ATOMIC_RELAXED, __HIP_MEMORY_SCOPE_AGENT);
            // 256 co-resident blocks; 8 pollers/line at ~430ns period -> no queue pressure.
            while (__hip_atomic_load(c, __ATOMIC_RELAXED, __HIP_MEMORY_SCOPE_AGENT) < BPS) {
                __builtin_amdgcn_s_sleep(16);
            }
            // gather the sample's 8 slots
            float gmn[3] = { FINF,  FINF,  FINF};
            float gmx[3] = {-FINF, -FINF, -FINF};
            const unsigned long long* base = partials + (size_t)(n * BPS) * 8;
#pragma unroll
            for (int s = 0; s < BPS; ++s) {
#pragma unroll
                for (int k = 0; k < 3; ++k) {
                    unsigned long long v =
                        __hip_atomic_load(&base[s * 8 + k], __ATOMIC_RELAXED, __HIP_MEMORY_SCOPE_AGENT);
                    gmn[k] = fminf(gmn[k], decf((unsigned)(v & 0xFFFFFFFFu)));
                    gmx[k] = fmaxf(gmx[k], decf((unsigned)(v >> 32)));
                }
            }
#pragma unroll
            for (int k = 0; k < 3; ++k) { s_min[k] = gmn[k]; s_max[k] = gmx[k]; }
        }
    }
    __syncthreads();

    // ---- phase 3: normalize from registers (no re-read), store ----
#pragma unroll
    for (int k = 0; k < 3; ++k) {
        const float pmin = s_min[k];
        const float inv  = 1.0f / (s_max[k] - pmin);
        float4* ob = (float4*)(out + (size_t)n * 3 * HW + (size_t)k * HW);

        float4 o;
        o.x = ((fmaf(w0[k], xA[0].x, fmaf(w1[k], xA[1].x, fmaf(w2[k], xA[2].x, bk[k]))) - pmin) * inv - 0.5f) * 2.0f;
        o.y = ((fmaf(w0[k], xA[0].y, fmaf(w1[k], xA[1].y, fmaf(w2[k], xA[2].y, bk[k]))) - pmin) * inv - 0.5f) * 2.0f;
        o.z = ((fmaf(w0[k], xA[0].z, fmaf(w1[k], xA[1].z, fmaf(w2[k], xA[2].z, bk[k]))) - pmin) * inv - 0.5f) * 2.0f;
        o.w = ((fmaf(w0[k], xA[0].w, fmaf(w1[k], xA[1].w, fmaf(w2[k], xA[2].w, bk[k]))) - pmin) * inv - 0.5f) * 2.0f;
        ob[sid] = o;
        // MAX_PERTURBATION / 128.0 == 1.0 — no extra scale.

        if (has2) {
            float4 q;
            q.x = ((fmaf(w0[k], xB[0].x, fmaf(w1[k], xB[1].x, fmaf(w2[k], xB[2].x, bk[k]))) - pmin) * inv - 0.5f) * 2.0f;
            q.y = ((fmaf(w0[k], xB[0].y, fmaf(w1[k], xB[1].y, fmaf(w2[k], xB[2].y, bk[k]))) - pmin) * inv - 0.5f) * 2.0f;
            q.z = ((fmaf(w0[k], xB[0].z, fmaf(w1[k], xB[1].z, fmaf(w2[k], xB[2].z, bk[k]))) - pmin) * inv - 0.5f) * 2.0f;
            q.w = ((fmaf(w0[k], xB[0].w, fmaf(w1[k], xB[1].w, fmaf(w2[k], xB[2].w, bk[k]))) - pmin) * inv - 0.5f) * 2.0f;
            ob[sid + TPS] = q;
        }
    }
}

extern "C" void kernel_launch(void* const* d_in, const int* in_sizes, int n_in,
                              void* d_out, int out_size, void* d_ws, size_t ws_size,
                              hipStream_t stream) {
    const float* x      = (const float*)d_in[0];
    const int*   target = (const int*)d_in[1];
    const float* W      = (const float*)d_in[2];
    const float* b      = (const float*)d_in[3];
    float*       out    = (float*)d_out;

    unsigned long long* partials = (unsigned long long*)d_ws;          // 16 KB
    unsigned*           cnt      = (unsigned*)((char*)d_ws + 16384);   // 2 KB

    init_kernel<<<1, 512, 0, stream>>>(cnt);
    fused_kernel<<<NBLK, NTHR, 0, stream>>>(x, target, W, b, partials, cnt, out);
}

// Round 8
// 15.164 us; speedup vs baseline: 5.9557x; 1.4364x over previous
//
#include <hip/hip_runtime.h>

// Problem geometry (fixed by reference):
//   x: (32, 3, 224, 224) f32, target: (32,) i32, W: (60,3,1,1) f32, b: (60,) f32
//   out: (32, 3, 224, 224) f32
#define HW    50176   // 224*224
#define HW4   12544   // HW/4 (float4 granules per channel)
#define NB    32      // batch
#define BPN   49      // blocks per sample: 12544 / 256
#define NTHR  256
#define FINF  __int_as_float(0x7f800000)

// Native clang vector type — required by __builtin_nontemporal_{load,store}
// (HIP_vector_type float4 is a struct and is rejected).
typedef float nfloat4 __attribute__((ext_vector_type(4)));

// ws layout: 6 floats per block: [pmin0,pmin1,pmin2,pmax0,pmax1,pmax2]
// All 1568*6 slots are unconditionally written by kernel 1 every call -> no
// init/memset needed, deterministic across graph replays.

__global__ __launch_bounds__(NTHR) void partial_minmax_kernel(
    const float* __restrict__ x, const int* __restrict__ target,
    const float* __restrict__ W, const float* __restrict__ b,
    float* __restrict__ ws)
{
    const int blk   = blockIdx.x;
    const int n     = blk / BPN;
    const int chunk = blk % BPN;
    const int idx4  = chunk * NTHR + threadIdx.x;   // [0, HW4)

    // Cached (non-NT) loads: pass 2 re-reads x from L2/L3.
    const nfloat4* xb = (const nfloat4*)(x + (size_t)n * 3 * HW);
    nfloat4 x0 = xb[idx4];
    nfloat4 x1 = xb[idx4 + HW4];
    nfloat4 x2 = xb[idx4 + 2 * HW4];

    const int t = target[n];

    float mn[3], mx[3];
#pragma unroll
    for (int k = 0; k < 3; ++k) {
        const int oc = t * 3 + k;
        const float w0 = W[oc * 3 + 0];
        const float w1 = W[oc * 3 + 1];
        const float w2 = W[oc * 3 + 2];
        const float bk = b[oc];
        float p0 = fmaf(w0, x0.x, fmaf(w1, x1.x, fmaf(w2, x2.x, bk)));
        float p1 = fmaf(w0, x0.y, fmaf(w1, x1.y, fmaf(w2, x2.y, bk)));
        float p2 = fmaf(w0, x0.z, fmaf(w1, x1.z, fmaf(w2, x2.z, bk)));
        float p3 = fmaf(w0, x0.w, fmaf(w1, x1.w, fmaf(w2, x2.w, bk)));
        mn[k] = fminf(fminf(p0, p1), fminf(p2, p3));
        mx[k] = fmaxf(fmaxf(p0, p1), fmaxf(p2, p3));
    }

    // wave-64 butterfly reduce
#pragma unroll
    for (int off = 32; off >= 1; off >>= 1) {
#pragma unroll
        for (int k = 0; k < 3; ++k) {
            mn[k] = fminf(mn[k], __shfl_xor(mn[k], off, 64));
            mx[k] = fmaxf(mx[k], __shfl_xor(mx[k], off, 64));
        }
    }

    __shared__ float smn[4][3], smx[4][3];
    const int lane = threadIdx.x & 63;
    const int wave = threadIdx.x >> 6;
    if (lane == 0) {
#pragma unroll
        for (int k = 0; k < 3; ++k) { smn[wave][k] = mn[k]; smx[wave][k] = mx[k]; }
    }
    __syncthreads();
    if (threadIdx.x == 0) {
        float* dst = ws + (size_t)blk * 6;
#pragma unroll
        for (int k = 0; k < 3; ++k) {
            dst[k]     = fminf(fminf(smn[0][k], smn[1][k]), fminf(smn[2][k], smn[3][k]));
            dst[k + 3] = fmaxf(fmaxf(smx[0][k], smx[1][k]), fmaxf(smx[2][k], smx[3][k]));
        }
    }
}

__global__ __launch_bounds__(NTHR) void apply_kernel(
    const float* __restrict__ x, const int* __restrict__ target,
    const float* __restrict__ W, const float* __restrict__ b,
    const float* __restrict__ ws, float* __restrict__ out)
{
    const int blk   = blockIdx.x;
    const int n     = blk / BPN;
    const int chunk = blk % BPN;
    const int idx4  = chunk * NTHR + threadIdx.x;

    // Last use of x: nontemporal loads (eviction hint; data comes from L2/L3).
    const nfloat4* xb = (const nfloat4*)(x + (size_t)n * 3 * HW);
    nfloat4 x0 = __builtin_nontemporal_load(&xb[idx4]);
    nfloat4 x1 = __builtin_nontemporal_load(&xb[idx4 + HW4]);
    nfloat4 x2 = __builtin_nontemporal_load(&xb[idx4 + 2 * HW4]);

    // Reduce this sample's 49 block-partials (L2/L3-resident, ~1.2 KB).
    __shared__ float s_min[3], s_max[3];
    if (threadIdx.x < 64) {
        const int lane = threadIdx.x;
        float mn[3] = { FINF,  FINF,  FINF};
        float mx[3] = {-FINF, -FINF, -FINF};
        if (lane < BPN) {
            const float* p = ws + (size_t)(n * BPN + lane) * 6;
#pragma unroll
            for (int k = 0; k < 3; ++k) { mn[k] = p[k]; mx[k] = p[k + 3]; }
        }
#pragma unroll
        for (int off = 32; off >= 1; off >>= 1) {
#pragma unroll
            for (int k = 0; k < 3; ++k) {
                mn[k] = fminf(mn[k], __shfl_xor(mn[k], off, 64));
                mx[k] = fmaxf(mx[k], __shfl_xor(mx[k], off, 64));
            }
        }
        if (lane == 0) {
#pragma unroll
            for (int k = 0; k < 3; ++k) { s_min[k] = mn[k]; s_max[k] = mx[k]; }
        }
    }
    __syncthreads();

    const int t = target[n];

#pragma unroll
    for (int k = 0; k < 3; ++k) {
        const int oc = t * 3 + k;
        const float w0 = W[oc * 3 + 0];
        const float w1 = W[oc * 3 + 1];
        const float w2 = W[oc * 3 + 2];
        const float bk = b[oc];
        const float pmin = s_min[k];
        const float inv  = 1.0f / (s_max[k] - pmin);

        float p0 = fmaf(w0, x0.x, fmaf(w1, x1.x, fmaf(w2, x2.x, bk)));
        float p1 = fmaf(w0, x0.y, fmaf(w1, x1.y, fmaf(w2, x2.y, bk)));
        float p2 = fmaf(w0, x0.z, fmaf(w1, x1.z, fmaf(w2, x2.z, bk)));
        float p3 = fmaf(w0, x0.w, fmaf(w1, x1.w, fmaf(w2, x2.w, bk)));

        nfloat4 o;
        o.x = ((p0 - pmin) * inv - 0.5f) * 2.0f;
        o.y = ((p1 - pmin) * inv - 0.5f) * 2.0f;
        o.z = ((p2 - pmin) * inv - 0.5f) * 2.0f;
        o.w = ((p3 - pmin) * inv - 0.5f) * 2.0f;
        // MAX_PERTURBATION / 128.0 == 1.0 — no extra scale needed.

        // out is never re-read: streaming (nontemporal) stores keep L2/L3 for x.
        nfloat4* ob = (nfloat4*)(out + (size_t)n * 3 * HW + (size_t)k * HW);
        __builtin_nontemporal_store(o, &ob[idx4]);
    }
}

extern "C" void kernel_launch(void* const* d_in, const int* in_sizes, int n_in,
                              void* d_out, int out_size, void* d_ws, size_t ws_size,
                              hipStream_t stream) {
    const float* x      = (const float*)d_in[0];
    const int*   target = (const int*)d_in[1];
    const float* W      = (const float*)d_in[2];
    const float* b      = (const float*)d_in[3];
    float*       out    = (float*)d_out;
    float*       ws     = (float*)d_ws;   // 1568 * 6 floats = 37.6 KB

    dim3 grid(NB * BPN);
    partial_minmax_kernel<<<grid, NTHR, 0, stream>>>(x, target, W, b, ws);
    apply_kernel<<<grid, NTHR, 0, stream>>>(x, target, W, b, ws, out);
}